// Round 5
// baseline (94555.847 us; speedup 1.0000x reference)
//
#include <hip/hip_runtime.h>
#include <hip/hip_bf16.h>
#include <hip/hip_cooperative_groups.h>

namespace cg = cooperative_groups;

#define BB   64
#define TENC 1024
#define DENC 256
#define HN   256
#define AN   128
#define NFC  10
#define EMBD 64
#define VN   96
#define TT   255

typedef unsigned short u16;

__device__ __forceinline__ float fsig(float x){ return 1.0f/(1.0f+__expf(-x)); }
__device__ __forceinline__ float ftanh(float x){ return 1.0f - 2.0f/(1.0f+__expf(2.0f*x)); }
__device__ __forceinline__ float b2f(u16 v){ return __uint_as_float(((unsigned)v) << 16); }
__device__ __forceinline__ u16 f2b(float x){
    __hip_bfloat16 h = __float2bfloat16(x);
    return *reinterpret_cast<u16*>(&h);
}
__device__ __forceinline__ float4 ld_bf4(const u16* p){
    ushort4 v = *(const ushort4*)p;
    return make_float4(b2f(v.x), b2f(v.y), b2f(v.z), b2f(v.w));
}

struct Params {
    const u16* encb; const u16* enc_projb; const u16* WdecTb;
    const float* conv_w; const float* W_loc; const float* v_w;
    const int* lengths; const int* targets; const float* emb;
    const float* WcombP; const float* biasw;
    const float* W1T; const float* out_b1; const float* W2T; const float* out_b2;
    float* e0; float* e1; float* ctxU0; float* ctxU1; float* SU0; float* SU1;
    float* h0; float* h1; float* c_st; float* hidA; float* hidB;
    float* out;
};

// ---------------- one-time prep: packed/transposed weights, bf16 copies, init ----------------
__global__ void k_prep(const float* __restrict__ enc,
                       const float* __restrict__ W_ih, const float* __restrict__ W_hh,
                       const float* __restrict__ b_ih, const float* __restrict__ b_hh,
                       const float* __restrict__ W_dec, const float* __restrict__ out_w1,
                       const float* __restrict__ out_w2,
                       u16* __restrict__ encb, u16* __restrict__ WdecTb,
                       float* __restrict__ WcombP, float* __restrict__ biasw,
                       float* __restrict__ W1T, float* __restrict__ W2T,
                       float* __restrict__ e_init, float* __restrict__ S_init)
{
    int tid = blockIdx.x*blockDim.x + threadIdx.x;
    int tot = blockDim.x*gridDim.x;
    // bf16 encoder copy
    for (size_t i = tid; i < (size_t)BB*TENC*DENC; i += tot) encb[i] = f2b(enc[i]);
    // WcombP[k][rowP], rowP = ug*16 + gidx*4 + ul  <->  g = gidx*256 + ug*4 + ul
    for (int i = tid; i < 576*1024; i += tot){
        int k = i >> 10, rp = i & 1023;
        int ug = rp >> 4, q = rp & 15, gidx = q >> 2, ul = q & 3;
        int g = gidx*256 + ug*4 + ul;
        WcombP[i] = (k < 320) ? W_ih[(size_t)g*320 + k] : W_hh[(size_t)g*256 + (k-320)];
    }
    for (int i = tid; i < 1024; i += tot) biasw[i] = b_ih[i] + b_hh[i];
    for (int i = tid; i < 256*128; i += tot){ int u = i>>7, a = i&127; WdecTb[i] = f2b(W_dec[a*256 + u]); }
    for (int i = tid; i < 512*256; i += tot){ int k = i>>8, r = i&255; W1T[i] = out_w1[(size_t)r*512 + k]; }
    for (int i = tid; i < 256*96;  i += tot){ int k = i/96, v = i - k*96; W2T[i] = out_w2[(size_t)v*256 + k]; }
    for (int i = tid; i < BB*TENC; i += tot) e_init[i] = 1.0f;
    for (int i = tid; i < BB; i += tot) S_init[i] = (float)TENC;
}

// ---------------- one-time: enc_projb[b,t,a] (bf16) ----------------
__global__ __launch_bounds__(128) void k_encproj(const float* __restrict__ enc,
                                                 const float* __restrict__ W_enc,
                                                 u16* __restrict__ enc_projb)
{
    __shared__ float rows[32][256];
    int r0 = blockIdx.x * 32;
    for (int i = threadIdx.x; i < 32*256; i += 128)
        rows[i>>8][i&255] = enc[(size_t)r0*256 + i];
    __syncthreads();
    int a = threadIdx.x;
    float acc[32];
    #pragma unroll
    for (int r=0;r<32;r++) acc[r]=0.f;
    const float* w = W_enc + a*256;
    for (int d=0; d<256; d+=4){
        float4 wv = *(const float4*)(w + d);
        #pragma unroll
        for (int r=0;r<32;r++){
            float4 rv = *(const float4*)(&rows[r][d]);
            acc[r] += wv.x*rv.x + wv.y*rv.y + wv.z*rv.z + wv.w*rv.w;
        }
    }
    for (int r=0;r<32;r++) enc_projb[(size_t)(r0+r)*AN + a] = f2b(acc[r]);
}

// ---------------- shared phase code ----------------
union alignas(16) SMem {
    struct { float hdec[128]; float part[256]; float ehalo[68]; float cw[52];
             float loc[64][11]; float wlocT[10*128]; float evals[64];
             float ep[64][33]; float wacc[4][256]; } att;
    struct { float xh[8][584]; float part[4][16][9]; float gates[8][17]; } gat;
    struct { float xh[8][520]; float part[4][16][9]; } hidm;
    struct { float hs[8][260]; float part[4][32][9]; } lgt;
};

// CELL: blocks [0,512) gates+LSTM; [512,640) hid(t-1); [640,664) logits(t-2)
__device__ __forceinline__ void cell_phase(const Params& P, int t, int blk, int tid, SMem& u)
{
    const int wr = t & 1;
    const float* ctxU_r = wr ? P.ctxU0 : P.ctxU1;
    float*       ctxU_w = wr ? P.ctxU1 : P.ctxU0;
    const float* SU_r   = wr ? P.SU0   : P.SU1;
    float*       SU_w   = wr ? P.SU1   : P.SU0;
    const float* h_old  = wr ? P.h0    : P.h1;
    float*       h_new  = wr ? P.h1    : P.h0;
    const float* hid_pv = wr ? P.hidA  : P.hidB;
    float*       hid_nw = wr ? P.hidB  : P.hidA;

    if (blk < 512){
        if (t > 254) return;
        const int ug = blk & 63, bg = blk >> 6;
        const int b0 = bg*8;
        if (ug == 1){   // zero next-step accumulators for this batch group
            for (int i = tid; i < 8*DENC; i += 256) ctxU_w[b0*DENC + i] = 0.f;
            if (tid < 8) SU_w[b0 + tid] = 0.f;
        }
        for (int i = tid; i < 8*EMBD; i += 256){
            int bl = i>>6, j = i&63;
            int tok = P.targets[(b0+bl)*256 + t];
            u.gat.xh[bl][j] = P.emb[tok*EMBD + j];
        }
        for (int i = tid; i < 8*HN; i += 256){
            int bl = i>>8, d = i&255;
            u.gat.xh[bl][320+d] = (t == 0) ? 0.f : h_old[(b0+bl)*HN + d];
        }
        for (int i = tid; i < 8*DENC; i += 256){
            int bl = i>>8, d = i&255;
            u.gat.xh[bl][64+d] = (t == 0) ? 0.f
                : ctxU_r[(b0+bl)*DENC + d] * (1.0f/SU_r[b0+bl]);
        }
        __syncthreads();
        {
            const int kq = tid >> 6, lane = tid & 63, rl = lane & 15, blq = lane >> 4;
            const int rowP = ug*16 + rl, bl0 = blq*2;
            const float* wp  = P.WcombP + (size_t)(kq*144)*1024 + rowP;
            const float* x0p = &u.gat.xh[bl0][kq*144];
            const float* x1p = &u.gat.xh[bl0+1][kq*144];
            float s0 = 0.f, s1 = 0.f;
            for (int k = 0; k < 144; k += 4){
                float w0 = wp[0], w1 = wp[1024], w2 = wp[2048], w3 = wp[3072]; wp += 4096;
                float4 xa = *(const float4*)(x0p + k);
                float4 xb = *(const float4*)(x1p + k);
                s0 += w0*xa.x + w1*xa.y + w2*xa.z + w3*xa.w;
                s1 += w0*xb.x + w1*xb.y + w2*xb.z + w3*xb.w;
            }
            u.gat.part[kq][rl][bl0] = s0; u.gat.part[kq][rl][bl0+1] = s1;
        }
        __syncthreads();
        if (tid < 128){
            int bl = tid >> 4, rl = tid & 15;
            float s = u.gat.part[0][rl][bl] + u.gat.part[1][rl][bl]
                    + u.gat.part[2][rl][bl] + u.gat.part[3][rl][bl];
            int gidx = rl >> 2, ul = rl & 3;
            u.gat.gates[bl][rl] = s + P.biasw[gidx*256 + ug*4 + ul];
        }
        __syncthreads();
        if (tid < 32){
            int bl = tid >> 2, ul = tid & 3;
            int bgl = b0 + bl, unit = ug*4 + ul;
            float gi = u.gat.gates[bl][0+ul],  gf = u.gat.gates[bl][4+ul];
            float gg = u.gat.gates[bl][8+ul],  go = u.gat.gates[bl][12+ul];
            float cold = (t == 0) ? 0.f : P.c_st[bgl*HN + unit];
            float cn = fsig(gf)*cold + fsig(gi)*ftanh(gg);
            P.c_st[bgl*HN + unit] = cn;
            h_new[bgl*HN + unit] = fsig(go)*ftanh(cn);
        }
        return;
    }

    if (blk < 640){
        if (!(t >= 1 && t <= 255)) return;
        int hb = blk - 512;
        int bg = hb >> 4, rg = hb & 15;
        int b0 = bg*8, r0 = rg*16;
        for (int i = tid; i < 8*HN; i += 256){
            int bl = i>>8, d = i&255;
            u.hidm.xh[bl][d] = h_old[(b0+bl)*HN + d];
        }
        for (int i = tid; i < 8*DENC; i += 256){
            int bl = i>>8, d = i&255;
            u.hidm.xh[bl][256+d] = ctxU_r[(b0+bl)*DENC + d] * (1.0f/SU_r[b0+bl]);
        }
        __syncthreads();
        {
            const int kq = tid >> 6, lane = tid & 63, rl = lane & 15, blq = lane >> 4;
            const int bl0 = blq*2;
            const float* wp  = P.W1T + (size_t)(kq*128)*256 + (r0 + rl);
            const float* x0p = &u.hidm.xh[bl0][kq*128];
            const float* x1p = &u.hidm.xh[bl0+1][kq*128];
            float s0 = 0.f, s1 = 0.f;
            for (int k = 0; k < 128; k += 4){
                float w0 = wp[0], w1 = wp[256], w2 = wp[512], w3 = wp[768]; wp += 1024;
                float4 xa = *(const float4*)(x0p + k);
                float4 xb = *(const float4*)(x1p + k);
                s0 += w0*xa.x + w1*xa.y + w2*xa.z + w3*xa.w;
                s1 += w0*xb.x + w1*xb.y + w2*xb.z + w3*xb.w;
            }
            u.hidm.part[kq][rl][bl0] = s0; u.hidm.part[kq][rl][bl0+1] = s1;
        }
        __syncthreads();
        if (tid < 128){
            int bl = tid >> 4, rl = tid & 15;
            int r = r0 + rl;
            float s = u.hidm.part[0][rl][bl] + u.hidm.part[1][rl][bl]
                    + u.hidm.part[2][rl][bl] + u.hidm.part[3][rl][bl];
            hid_nw[(b0+bl)*HN + r] = ftanh(s + P.out_b1[r]);
        }
        return;
    }

    if (blk < 664){
        if (t < 2) return;
        int lt = blk - 640;
        int bgr = lt/3, vg = lt%3;
        int b0 = bgr*8, v0 = vg*32;
        for (int i = tid; i < 8*HN; i += 256){
            int bl = i>>8, d = i&255;
            u.lgt.hs[bl][d] = hid_pv[(b0+bl)*HN + d];
        }
        __syncthreads();
        {
            const int kq = tid >> 6, lane = tid & 63, vl = lane & 31, blq = lane >> 5;
            const int bl0 = blq*4;
            const float* wp = P.W2T + (size_t)(kq*64)*96 + (v0 + vl);
            float a4[4] = {0.f,0.f,0.f,0.f};
            for (int k = 0; k < 64; k += 4){
                float w0 = wp[0], w1 = wp[96], w2 = wp[192], w3 = wp[288]; wp += 384;
                #pragma unroll
                for (int j = 0; j < 4; j++){
                    float4 x = *(const float4*)&u.lgt.hs[bl0+j][kq*64 + k];
                    a4[j] += w0*x.x + w1*x.y + w2*x.z + w3*x.w;
                }
            }
            #pragma unroll
            for (int j = 0; j < 4; j++) u.lgt.part[kq][vl][bl0+j] = a4[j];
        }
        __syncthreads();
        {
            int bl = tid >> 5, vl = tid & 31;
            int v = v0 + vl;
            float s = u.lgt.part[0][vl][bl] + u.lgt.part[1][vl][bl]
                    + u.lgt.part[2][vl][bl] + u.lgt.part[3][vl][bl];
            P.out[((size_t)(b0+bl)*TT + (t-2))*VN + v] = s + P.out_b2[v];
        }
    }
}

// ATT: 1024 blocks = (ch 16) x (b 64), chunk-major: b = blk & 63 pins batch -> XCD
__device__ __forceinline__ void att_phase(const Params& P, int t, int blk, int tid, SMem& u)
{
    if (t > 254) return;
    const int wr = t & 1;
    float*       ctxU_w = wr ? P.ctxU1 : P.ctxU0;
    const float* SU_r   = wr ? P.SU0   : P.SU1;
    float*       SU_w   = wr ? P.SU1   : P.SU0;
    const float* h_new  = wr ? P.h1    : P.h0;
    const float* e_prev = wr ? P.e0    : P.e1;
    float*       e_new  = wr ? P.e1    : P.e0;

    const int b  = blk & 63;
    const int ch = blk >> 6;          // [0,16)
    const int t0 = ch*64;
    float* e_row = e_new + b*TENC + t0;

    const int len = P.lengths[b];
    int nv = len - t0; nv = nv < 0 ? 0 : (nv > 64 ? 64 : nv);
    if (nv == 0){
        if (tid < 64) e_row[tid] = 0.f;
        return;
    }

    // stage small tables + halo
    if (tid < 50) u.att.cw[tid] = P.conv_w[tid];
    for (int i = tid; i < 1280; i += 256){
        int f = i >> 7, a = i & 127;
        u.att.wlocT[f*128 + a] = P.W_loc[a*NFC + f];
    }
    if (tid < 68){
        int g = t0 - 2 + tid;
        u.att.ehalo[tid] = (g >= 0 && g < TENC) ? e_prev[b*TENC + g] : 0.f;
    }
    {   // hdec partials: thread (a, half)
        int a = tid & 127, half = tid >> 7;
        const u16* wd = P.WdecTb + (size_t)(half*128)*AN + a;
        const float* hb = h_new + b*HN + half*128;
        float s0 = 0.f, s1 = 0.f;
        #pragma unroll 4
        for (int uu = 0; uu < 128; uu += 2){
            s0 += hb[uu]   * b2f(wd[(size_t)uu*AN]);
            s1 += hb[uu+1] * b2f(wd[(size_t)(uu+1)*AN]);
        }
        u.att.part[tid] = s0 + s1;
    }
    __syncthreads();
    if (tid < 128){
        u.att.hdec[tid] = u.att.part[tid] + u.att.part[tid+128];
    } else if (tid >= 192){   // conv for p = tid-192 (runs parallel with hdec reduce)
        int p = tid - 192;
        float invS = 1.0f / SU_r[b];
        #pragma unroll
        for (int f = 0; f < NFC; f++){
            float s = 0.f;
            #pragma unroll
            for (int k2 = 0; k2 < 5; k2++) s += u.att.ehalo[p+k2] * u.att.cw[f*5+k2];
            u.att.loc[p][f] = s * invS;
        }
    }
    __syncthreads();

    // energy partials: thread = (ag 32) x (pg 8), 8 positions each
    {
        const int ag = tid & 31, pg = tid >> 5;
        const int a0 = ag*4;
        float4 hd4 = *(const float4*)&u.att.hdec[a0];
        float4 vv  = *(const float4*)(P.v_w + a0);
        const u16* epr = P.enc_projb + ((size_t)(b*TENC + t0))*AN + a0;
        #pragma unroll
        for (int i = 0; i < 8; i++){
            int p = pg*8 + i;
            float4 er = ld_bf4(epr + (size_t)p*AN);
            float x0 = er.x + hd4.x, x1 = er.y + hd4.y;
            float x2 = er.z + hd4.z, x3 = er.w + hd4.w;
            #pragma unroll
            for (int f = 0; f < NFC; f++){
                float lf = u.att.loc[p][f];
                const float* wla = &u.att.wlocT[f*128 + a0];
                x0 += lf*wla[0]; x1 += lf*wla[1]; x2 += lf*wla[2]; x3 += lf*wla[3];
            }
            u.att.ep[p][ag] = vv.x*ftanh(x0) + vv.y*ftanh(x1)
                            + vv.z*ftanh(x2) + vv.w*ftanh(x3);
        }
    }
    __syncthreads();

    // finalize e + S (wave 0)
    if (tid < 64){
        int p = tid;
        float s0 = 0.f, s1 = 0.f;
        #pragma unroll
        for (int j = 0; j < 32; j += 2){ s0 += u.att.ep[p][j]; s1 += u.att.ep[p][j+1]; }
        float e = (p < nv) ? __expf(s0 + s1) : 0.f;   // |energy| <= sum|v| ~ 5.2
        u.att.evals[p] = e;
        e_row[p] = e;
        float se = e;
        #pragma unroll
        for (int off = 32; off; off >>= 1) se += __shfl_xor(se, off);
        if (tid == 0) atomicAdd(SU_w + b, se);
    }
    __syncthreads();

    // unnormalized ctx: thread = (dq 64) x (pq 4), branch-free (evals zero-padded)
    {
        const int dq = tid & 63, pq = tid >> 6;
        const u16* encb = P.encb + ((size_t)(b*TENC + t0))*DENC + dq*4;
        float ax=0.f, ay=0.f, az=0.f, aw=0.f;
        #pragma unroll
        for (int i = 0; i < 16; i++){
            int p = pq + i*4;
            float ev = u.att.evals[p];
            float4 ex = ld_bf4(encb + (size_t)p*DENC);
            ax += ev*ex.x; ay += ev*ex.y; az += ev*ex.z; aw += ev*ex.w;
        }
        float4 r; r.x=ax; r.y=ay; r.z=az; r.w=aw;
        *(float4*)&u.att.wacc[pq][dq*4] = r;
    }
    __syncthreads();
    {
        int d = tid;
        float s = u.att.wacc[0][d] + u.att.wacc[1][d]
                + u.att.wacc[2][d] + u.att.wacc[3][d];
        atomicAdd(ctxU_w + b*DENC + d, s);
    }
}

// ---------------- persistent cooperative loop (1024 x 256) ----------------
__global__ __launch_bounds__(256, 4) void k_loop(Params P)
{
    cg::grid_group grid = cg::this_grid();
    __shared__ SMem u;
    for (int t = 0; t <= 256; t++){
        cell_phase(P, t, blockIdx.x, threadIdx.x, u);
        grid.sync();
        att_phase(P, t, blockIdx.x, threadIdx.x, u);
        grid.sync();
    }
}

// ---------------- per-step fallback kernels (same phase code) ----------------
__global__ __launch_bounds__(256, 4) void k_cell_step(Params P, int t)
{
    __shared__ SMem u;
    cell_phase(P, t, blockIdx.x, threadIdx.x, u);
}
__global__ __launch_bounds__(256, 4) void k_att_step(Params P, int t)
{
    __shared__ SMem u;
    att_phase(P, t, blockIdx.x, threadIdx.x, u);
}

extern "C" void kernel_launch(void* const* d_in, const int* in_sizes, int n_in,
                              void* d_out, int out_size, void* d_ws, size_t ws_size,
                              hipStream_t stream)
{
    const float* enc     = (const float*)d_in[0];
    const int*   lengths = (const int*)  d_in[1];
    const int*   targets = (const int*)  d_in[2];
    const float* emb     = (const float*)d_in[3];
    const float* W_ih    = (const float*)d_in[4];
    const float* W_hh    = (const float*)d_in[5];
    const float* b_ih    = (const float*)d_in[6];
    const float* b_hh    = (const float*)d_in[7];
    const float* conv_w  = (const float*)d_in[8];
    const float* W_enc   = (const float*)d_in[9];
    const float* W_dec   = (const float*)d_in[10];
    const float* W_loc   = (const float*)d_in[11];
    const float* v_w     = (const float*)d_in[12];
    const float* out_w1  = (const float*)d_in[13];
    const float* out_b1  = (const float*)d_in[14];
    const float* out_w2  = (const float*)d_in[15];
    const float* out_b2  = (const float*)d_in[16];
    float* out = (float*)d_out;

    float* ws = (float*)d_ws;
    size_t off = 0;
    auto alloc = [&](size_t n){ float* p = ws + off; off += n; return p; };
    u16*   encb      = (u16*)  alloc((size_t)BB*TENC*DENC/2);
    u16*   enc_projb = (u16*)  alloc((size_t)BB*TENC*AN/2);
    u16*   WdecTb    = (u16*)  alloc(256*128/2);
    float* WcombP    = alloc(576*1024);
    float* biasw     = alloc(1024);
    float* W1T       = alloc(512*256);
    float* W2T       = alloc(256*96);
    float* e0        = alloc(BB*TENC);
    float* e1        = alloc(BB*TENC);
    float* ctxU0     = alloc(BB*DENC);
    float* ctxU1     = alloc(BB*DENC);
    float* SU0       = alloc(BB);
    float* SU1       = alloc(BB);
    float* h0        = alloc(BB*HN);
    float* h1        = alloc(BB*HN);
    float* c_st      = alloc(BB*HN);
    float* hidA      = alloc(BB*HN);
    float* hidB      = alloc(BB*HN);
    if (off * sizeof(float) > ws_size) return;   // visible failure if ws too small

    k_prep<<<dim3(512), dim3(256), 0, stream>>>(enc, W_ih, W_hh, b_ih, b_hh, W_dec,
                                                out_w1, out_w2,
                                                encb, WdecTb, WcombP, biasw, W1T, W2T,
                                                e1, SU1);
    k_encproj<<<dim3(2048), dim3(128), 0, stream>>>(enc, W_enc, enc_projb);

    Params pr;
    pr.encb = encb; pr.enc_projb = enc_projb; pr.WdecTb = WdecTb;
    pr.conv_w = conv_w; pr.W_loc = W_loc; pr.v_w = v_w;
    pr.lengths = lengths; pr.targets = targets; pr.emb = emb;
    pr.WcombP = WcombP; pr.biasw = biasw;
    pr.W1T = W1T; pr.out_b1 = out_b1; pr.W2T = W2T; pr.out_b2 = out_b2;
    pr.e0 = e0; pr.e1 = e1; pr.ctxU0 = ctxU0; pr.ctxU1 = ctxU1;
    pr.SU0 = SU0; pr.SU1 = SU1; pr.h0 = h0; pr.h1 = h1;
    pr.c_st = c_st; pr.hidA = hidA; pr.hidB = hidB; pr.out = out;

    void* args[] = { (void*)&pr };
    hipError_t err = hipLaunchCooperativeKernel((const void*)k_loop, dim3(1024), dim3(256),
                                                args, 0, stream);
    if (err != hipSuccess){
        // deterministic fallback: same phase code, per-step launches
        for (int t = 0; t <= 256; t++){
            k_cell_step<<<dim3(1024), dim3(256), 0, stream>>>(pr, t);
            if (t <= 254)
                k_att_step<<<dim3(1024), dim3(256), 0, stream>>>(pr, t);
        }
    }
}

// Round 6
// 67428.192 us; speedup vs baseline: 1.4023x; 1.4023x over previous
//
#include <hip/hip_runtime.h>
#include <hip/hip_bf16.h>
#include <hip/hip_cooperative_groups.h>

namespace cg = cooperative_groups;

#define BB   64
#define TENC 1024
#define DENC 256
#define HN   256
#define AN   128
#define NFC  10
#define EMBD 64
#define VN   96
#define TT   255

typedef unsigned short u16;

__device__ __forceinline__ float fsig(float x){ return 1.0f/(1.0f+__expf(-x)); }
__device__ __forceinline__ float ftanh(float x){ return 1.0f - 2.0f/(1.0f+__expf(2.0f*x)); }
__device__ __forceinline__ float b2f(u16 v){ return __uint_as_float(((unsigned)v) << 16); }
__device__ __forceinline__ u16 f2b(float x){
    __hip_bfloat16 h = __float2bfloat16(x);
    return *reinterpret_cast<u16*>(&h);
}
__device__ __forceinline__ float4 ld_bf4(const u16* p){
    ushort4 v = *(const ushort4*)p;
    return make_float4(b2f(v.x), b2f(v.y), b2f(v.z), b2f(v.w));
}

struct Params {
    const u16* encb; const u16* enc_projb; const u16* WdecTb;
    const float* conv_w; const float* W_loc; const float* v_w;
    const int* lengths; const int* targets; const float* emb;
    const float* WcombP; const float* biasw;
    const float* W1T; const float* out_b1; const float* W2T; const float* out_b2;
    float* e0; float* e1; float* ctxU0; float* ctxU1; float* SU0; float* SU1;
    float* h0; float* h1; float* c_st; float* hidA; float* hidB;
    float* out;
};

// ---------------- one-time prep ----------------
__global__ void k_prep(const float* __restrict__ enc,
                       const float* __restrict__ W_ih, const float* __restrict__ W_hh,
                       const float* __restrict__ b_ih, const float* __restrict__ b_hh,
                       const float* __restrict__ W_dec, const float* __restrict__ out_w1,
                       const float* __restrict__ out_w2,
                       u16* __restrict__ encb, u16* __restrict__ WdecTb,
                       float* __restrict__ WcombP, float* __restrict__ biasw,
                       float* __restrict__ W1T, float* __restrict__ W2T,
                       float* __restrict__ e_init, float* __restrict__ S_init)
{
    int tid = blockIdx.x*blockDim.x + threadIdx.x;
    int tot = blockDim.x*gridDim.x;
    for (size_t i = tid; i < (size_t)BB*TENC*DENC; i += tot) encb[i] = f2b(enc[i]);
    // WcombP[k][rowP], rowP = ug*16 + gidx*4 + ul  <->  g = gidx*256 + ug*4 + ul
    for (int i = tid; i < 576*1024; i += tot){
        int k = i >> 10, rp = i & 1023;
        int ug = rp >> 4, q = rp & 15, gidx = q >> 2, ul = q & 3;
        int g = gidx*256 + ug*4 + ul;
        WcombP[i] = (k < 320) ? W_ih[(size_t)g*320 + k] : W_hh[(size_t)g*256 + (k-320)];
    }
    for (int i = tid; i < 1024; i += tot) biasw[i] = b_ih[i] + b_hh[i];
    for (int i = tid; i < 256*128; i += tot){ int u = i>>7, a = i&127; WdecTb[i] = f2b(W_dec[a*256 + u]); }
    for (int i = tid; i < 512*256; i += tot){ int k = i>>8, r = i&255; W1T[i] = out_w1[(size_t)r*512 + k]; }
    for (int i = tid; i < 256*96;  i += tot){ int k = i/96, v = i - k*96; W2T[i] = out_w2[(size_t)v*256 + k]; }
    for (int i = tid; i < BB*TENC; i += tot) e_init[i] = 1.0f;
    for (int i = tid; i < BB; i += tot) S_init[i] = (float)TENC;
}

// ---------------- one-time: enc_projb[b,t,a] (bf16) ----------------
__global__ __launch_bounds__(128) void k_encproj(const float* __restrict__ enc,
                                                 const float* __restrict__ W_enc,
                                                 u16* __restrict__ enc_projb)
{
    __shared__ float rows[32][256];
    int r0 = blockIdx.x * 32;
    for (int i = threadIdx.x; i < 32*256; i += 128)
        rows[i>>8][i&255] = enc[(size_t)r0*256 + i];
    __syncthreads();
    int a = threadIdx.x;
    float acc[32];
    #pragma unroll
    for (int r=0;r<32;r++) acc[r]=0.f;
    const float* w = W_enc + a*256;
    for (int d=0; d<256; d+=4){
        float4 wv = *(const float4*)(w + d);
        #pragma unroll
        for (int r=0;r<32;r++){
            float4 rv = *(const float4*)(&rows[r][d]);
            acc[r] += wv.x*rv.x + wv.y*rv.y + wv.z*rv.z + wv.w*rv.w;
        }
    }
    for (int r=0;r<32;r++) enc_projb[(size_t)(r0+r)*AN + a] = f2b(acc[r]);
}

// ---------------- shared phase code ----------------
union alignas(16) SMem {
    struct { float hdec[128]; float part[256]; float ehalo[68]; float cw[52];
             float loc[64][11]; float wlocT[10*128]; float evals[64];
             float ep[64][33]; float wacc[4][256]; } att;
    struct { float xh[8][584]; float part[4][16][9]; float gates[8][17]; } gat;
    struct { float xh[8][520]; float part[4][16][9]; } hidm;
    struct { float hs[8][260]; float part[4][32][9]; } lgt;
};

// CELL on 512 blocks: gates 1:1 on [0,512); hid(t-1) on [256,384); logits(t-2) on [384,408)
__device__ __forceinline__ void cell_phase(const Params& P, int t, int blk, int tid, SMem& u)
{
    const int wr = t & 1;
    const float* ctxU_r = wr ? P.ctxU0 : P.ctxU1;
    float*       ctxU_w = wr ? P.ctxU1 : P.ctxU0;
    const float* SU_r   = wr ? P.SU0   : P.SU1;
    float*       SU_w   = wr ? P.SU1   : P.SU0;
    const float* h_old  = wr ? P.h0    : P.h1;
    float*       h_new  = wr ? P.h1    : P.h0;
    const float* hid_pv = wr ? P.hidA  : P.hidB;
    float*       hid_nw = wr ? P.hidB  : P.hidA;

    if (t <= 254){   // gates task (all 512 blocks)
        const int ug = blk & 63, bg = blk >> 6;
        const int b0 = bg*8;
        if (ug == 1){   // zero next-step accumulators for this batch group
            for (int i = tid; i < 8*DENC; i += 256) ctxU_w[b0*DENC + i] = 0.f;
            if (tid < 8) SU_w[b0 + tid] = 0.f;
        }
        for (int i = tid; i < 8*EMBD; i += 256){
            int bl = i>>6, j = i&63;
            int tok = P.targets[(b0+bl)*256 + t];
            u.gat.xh[bl][j] = P.emb[tok*EMBD + j];
        }
        for (int i = tid; i < 8*HN; i += 256){
            int bl = i>>8, d = i&255;
            u.gat.xh[bl][320+d] = (t == 0) ? 0.f : h_old[(b0+bl)*HN + d];
        }
        for (int i = tid; i < 8*DENC; i += 256){
            int bl = i>>8, d = i&255;
            u.gat.xh[bl][64+d] = (t == 0) ? 0.f
                : ctxU_r[(b0+bl)*DENC + d] * (1.0f/SU_r[b0+bl]);
        }
        __syncthreads();
        {
            const int kq = tid >> 6, lane = tid & 63, rl = lane & 15, blq = lane >> 4;
            const int rowP = ug*16 + rl, bl0 = blq*2;
            const float* wp  = P.WcombP + (size_t)(kq*144)*1024 + rowP;
            const float* x0p = &u.gat.xh[bl0][kq*144];
            const float* x1p = &u.gat.xh[bl0+1][kq*144];
            float s0 = 0.f, s1 = 0.f;
            for (int k = 0; k < 144; k += 4){
                float w0 = wp[0], w1 = wp[1024], w2 = wp[2048], w3 = wp[3072]; wp += 4096;
                float4 xa = *(const float4*)(x0p + k);
                float4 xb = *(const float4*)(x1p + k);
                s0 += w0*xa.x + w1*xa.y + w2*xa.z + w3*xa.w;
                s1 += w0*xb.x + w1*xb.y + w2*xb.z + w3*xb.w;
            }
            u.gat.part[kq][rl][bl0] = s0; u.gat.part[kq][rl][bl0+1] = s1;
        }
        __syncthreads();
        if (tid < 128){
            int bl = tid >> 4, rl = tid & 15;
            float s = u.gat.part[0][rl][bl] + u.gat.part[1][rl][bl]
                    + u.gat.part[2][rl][bl] + u.gat.part[3][rl][bl];
            int gidx = rl >> 2, ul = rl & 3;
            u.gat.gates[bl][rl] = s + P.biasw[gidx*256 + ug*4 + ul];
        }
        __syncthreads();
        if (tid < 32){
            int bl = tid >> 2, ul = tid & 3;
            int bgl = b0 + bl, unit = ug*4 + ul;
            float gi = u.gat.gates[bl][0+ul],  gf = u.gat.gates[bl][4+ul];
            float gg = u.gat.gates[bl][8+ul],  go = u.gat.gates[bl][12+ul];
            float cold = (t == 0) ? 0.f : P.c_st[bgl*HN + unit];
            float cn = fsig(gf)*cold + fsig(gi)*ftanh(gg);
            P.c_st[bgl*HN + unit] = cn;
            h_new[bgl*HN + unit] = fsig(go)*ftanh(cn);
        }
        __syncthreads();
    }

    if (blk >= 256 && blk < 384 && t >= 1 && t <= 255){   // hid(t-1)
        int hb = blk - 256;
        int bg = hb >> 4, rg = hb & 15;
        int b0 = bg*8, r0 = rg*16;
        for (int i = tid; i < 8*HN; i += 256){
            int bl = i>>8, d = i&255;
            u.hidm.xh[bl][d] = h_old[(b0+bl)*HN + d];
        }
        for (int i = tid; i < 8*DENC; i += 256){
            int bl = i>>8, d = i&255;
            u.hidm.xh[bl][256+d] = ctxU_r[(b0+bl)*DENC + d] * (1.0f/SU_r[b0+bl]);
        }
        __syncthreads();
        {
            const int kq = tid >> 6, lane = tid & 63, rl = lane & 15, blq = lane >> 4;
            const int bl0 = blq*2;
            const float* wp  = P.W1T + (size_t)(kq*128)*256 + (r0 + rl);
            const float* x0p = &u.hidm.xh[bl0][kq*128];
            const float* x1p = &u.hidm.xh[bl0+1][kq*128];
            float s0 = 0.f, s1 = 0.f;
            for (int k = 0; k < 128; k += 4){
                float w0 = wp[0], w1 = wp[256], w2 = wp[512], w3 = wp[768]; wp += 1024;
                float4 xa = *(const float4*)(x0p + k);
                float4 xb = *(const float4*)(x1p + k);
                s0 += w0*xa.x + w1*xa.y + w2*xa.z + w3*xa.w;
                s1 += w0*xb.x + w1*xb.y + w2*xb.z + w3*xb.w;
            }
            u.hidm.part[kq][rl][bl0] = s0; u.hidm.part[kq][rl][bl0+1] = s1;
        }
        __syncthreads();
        if (tid < 128){
            int bl = tid >> 4, rl = tid & 15;
            int r = r0 + rl;
            float s = u.hidm.part[0][rl][bl] + u.hidm.part[1][rl][bl]
                    + u.hidm.part[2][rl][bl] + u.hidm.part[3][rl][bl];
            hid_nw[(b0+bl)*HN + r] = ftanh(s + P.out_b1[r]);
        }
    }

    if (blk >= 384 && blk < 408 && t >= 2){   // logits(t-2)
        int lt = blk - 384;
        int bgr = lt/3, vg = lt%3;
        int b0 = bgr*8, v0 = vg*32;
        for (int i = tid; i < 8*HN; i += 256){
            int bl = i>>8, d = i&255;
            u.lgt.hs[bl][d] = hid_pv[(b0+bl)*HN + d];
        }
        __syncthreads();
        {
            const int kq = tid >> 6, lane = tid & 63, vl = lane & 31, blq = lane >> 5;
            const int bl0 = blq*4;
            const float* wp = P.W2T + (size_t)(kq*64)*96 + (v0 + vl);
            float a4[4] = {0.f,0.f,0.f,0.f};
            for (int k = 0; k < 64; k += 4){
                float w0 = wp[0], w1 = wp[96], w2 = wp[192], w3 = wp[288]; wp += 384;
                #pragma unroll
                for (int j = 0; j < 4; j++){
                    float4 x = *(const float4*)&u.lgt.hs[bl0+j][kq*64 + k];
                    a4[j] += w0*x.x + w1*x.y + w2*x.z + w3*x.w;
                }
            }
            #pragma unroll
            for (int j = 0; j < 4; j++) u.lgt.part[kq][vl][bl0+j] = a4[j];
        }
        __syncthreads();
        {
            int bl = tid >> 5, vl = tid & 31;
            int v = v0 + vl;
            float s = u.lgt.part[0][vl][bl] + u.lgt.part[1][vl][bl]
                    + u.lgt.part[2][vl][bl] + u.lgt.part[3][vl][bl];
            P.out[((size_t)(b0+bl)*TT + (t-2))*VN + v] = s + P.out_b2[v];
        }
    }
}

// ATT on 512 blocks: b = blk>>3, chunks (blk&7) and (blk&7)+8
__device__ __forceinline__ void att_phase(const Params& P, int t, int blk, int tid, SMem& u)
{
    if (t > 254) return;
    const int wr = t & 1;
    float*       ctxU_w = wr ? P.ctxU1 : P.ctxU0;
    const float* SU_r   = wr ? P.SU0   : P.SU1;
    float*       SU_w   = wr ? P.SU1   : P.SU0;
    const float* h_new  = wr ? P.h1    : P.h0;
    const float* e_prev = wr ? P.e0    : P.e1;
    float*       e_new  = wr ? P.e1    : P.e0;

    const int b = blk >> 3;
    const int q = blk & 7;
    const int len = P.lengths[b];
    const float invS = 1.0f / SU_r[b];

    // small tables
    if (tid < 50) u.att.cw[tid] = P.conv_w[tid];
    for (int i = tid; i < 1280; i += 256){
        int f = i >> 7, a = i & 127;
        u.att.wlocT[f*128 + a] = P.W_loc[a*NFC + f];
    }
    {   // hdec partials: thread (a, half)
        int a = tid & 127, half = tid >> 7;
        const u16* wd = P.WdecTb + (size_t)(half*128)*AN + a;
        const float* hb = h_new + b*HN + half*128;
        float s0 = 0.f, s1 = 0.f;
        #pragma unroll 4
        for (int uu = 0; uu < 128; uu += 2){
            s0 += hb[uu]   * b2f(wd[(size_t)uu*AN]);
            s1 += hb[uu+1] * b2f(wd[(size_t)(uu+1)*AN]);
        }
        u.att.part[tid] = s0 + s1;
    }
    __syncthreads();
    if (tid < 128) u.att.hdec[tid] = u.att.part[tid] + u.att.part[tid+128];
    __syncthreads();

    for (int kk = 0; kk < 2; kk++){
        const int ch = q + 8*kk;
        const int t0 = ch*64;
        float* e_row = e_new + b*TENC + t0;
        int nv = len - t0; nv = nv < 0 ? 0 : (nv > 64 ? 64 : nv);
        if (nv == 0){
            if (tid < 64) e_row[tid] = 0.f;
            continue;
        }
        __syncthreads();
        if (tid < 68){
            int g = t0 - 2 + tid;
            u.att.ehalo[tid] = (g >= 0 && g < TENC) ? e_prev[b*TENC + g] : 0.f;
        }
        __syncthreads();
        if (tid < 64){
            #pragma unroll
            for (int f = 0; f < NFC; f++){
                float s = 0.f;
                #pragma unroll
                for (int k2 = 0; k2 < 5; k2++) s += u.att.ehalo[tid+k2] * u.att.cw[f*5+k2];
                u.att.loc[tid][f] = s * invS;
            }
        }
        __syncthreads();

        // energy partials: thread = (ag 32) x (pg 8), 8 positions each, predicated
        {
            const int ag = tid & 31, pg = tid >> 5;
            const int a0 = ag*4;
            float4 hd4 = *(const float4*)&u.att.hdec[a0];
            float4 vv  = *(const float4*)(P.v_w + a0);
            const u16* epr = P.enc_projb + ((size_t)(b*TENC + t0))*AN + a0;
            #pragma unroll
            for (int i = 0; i < 8; i++){
                int p = pg*8 + i;
                if (p < nv){
                    float4 er = ld_bf4(epr + (size_t)p*AN);
                    float x0 = er.x + hd4.x, x1 = er.y + hd4.y;
                    float x2 = er.z + hd4.z, x3 = er.w + hd4.w;
                    #pragma unroll
                    for (int f = 0; f < NFC; f++){
                        float lf = u.att.loc[p][f];
                        const float* wla = &u.att.wlocT[f*128 + a0];
                        x0 += lf*wla[0]; x1 += lf*wla[1]; x2 += lf*wla[2]; x3 += lf*wla[3];
                    }
                    u.att.ep[p][ag] = vv.x*ftanh(x0) + vv.y*ftanh(x1)
                                    + vv.z*ftanh(x2) + vv.w*ftanh(x3);
                }
            }
        }
        __syncthreads();

        if (tid < 64){
            int p = tid;
            float e = 0.f;
            if (p < nv){
                float s0 = 0.f, s1 = 0.f;
                #pragma unroll
                for (int j = 0; j < 32; j += 2){ s0 += u.att.ep[p][j]; s1 += u.att.ep[p][j+1]; }
                e = __expf(s0 + s1);   // |energy| <= sum|v| ~ 5.2
            }
            u.att.evals[p] = e;
            e_row[p] = e;
            float se = e;
            #pragma unroll
            for (int off = 32; off; off >>= 1) se += __shfl_xor(se, off);
            if (tid == 0) atomicAdd(SU_w + b, se);
        }
        __syncthreads();

        // unnormalized ctx: thread = (dq 64) x (pq 4), predicated
        {
            const int dq = tid & 63, pq = tid >> 6;
            const u16* encb = P.encb + ((size_t)(b*TENC + t0))*DENC + dq*4;
            float ax=0.f, ay=0.f, az=0.f, aw=0.f;
            for (int i = 0; i < 16; i++){
                int p = pq + i*4;
                if (p < nv){
                    float ev = u.att.evals[p];
                    float4 ex = ld_bf4(encb + (size_t)p*DENC);
                    ax += ev*ex.x; ay += ev*ex.y; az += ev*ex.z; aw += ev*ex.w;
                }
            }
            float4 r; r.x=ax; r.y=ay; r.z=az; r.w=aw;
            *(float4*)&u.att.wacc[pq][dq*4] = r;
        }
        __syncthreads();
        {
            int d = tid;
            float s = u.att.wacc[0][d] + u.att.wacc[1][d]
                    + u.att.wacc[2][d] + u.att.wacc[3][d];
            atomicAdd(ctxU_w + b*DENC + d, s);
        }
        __syncthreads();
    }
}

// ---------------- persistent cooperative loop (512 x 256) ----------------
__global__ __launch_bounds__(256, 2) void k_loop(Params P)
{
    cg::grid_group grid = cg::this_grid();
    __shared__ SMem u;
    for (int t = 0; t <= 256; t++){
        cell_phase(P, t, blockIdx.x, threadIdx.x, u);
        grid.sync();
        att_phase(P, t, blockIdx.x, threadIdx.x, u);
        grid.sync();
    }
}

// ---------------- per-step fallback kernels (same phase code) ----------------
__global__ __launch_bounds__(256, 2) void k_cell_step(Params P, int t)
{
    __shared__ SMem u;
    cell_phase(P, t, blockIdx.x, threadIdx.x, u);
}
__global__ __launch_bounds__(256, 2) void k_att_step(Params P, int t)
{
    __shared__ SMem u;
    att_phase(P, t, blockIdx.x, threadIdx.x, u);
}

extern "C" void kernel_launch(void* const* d_in, const int* in_sizes, int n_in,
                              void* d_out, int out_size, void* d_ws, size_t ws_size,
                              hipStream_t stream)
{
    const float* enc     = (const float*)d_in[0];
    const int*   lengths = (const int*)  d_in[1];
    const int*   targets = (const int*)  d_in[2];
    const float* emb     = (const float*)d_in[3];
    const float* W_ih    = (const float*)d_in[4];
    const float* W_hh    = (const float*)d_in[5];
    const float* b_ih    = (const float*)d_in[6];
    const float* b_hh    = (const float*)d_in[7];
    const float* conv_w  = (const float*)d_in[8];
    const float* W_enc   = (const float*)d_in[9];
    const float* W_dec   = (const float*)d_in[10];
    const float* W_loc   = (const float*)d_in[11];
    const float* v_w     = (const float*)d_in[12];
    const float* out_w1  = (const float*)d_in[13];
    const float* out_b1  = (const float*)d_in[14];
    const float* out_w2  = (const float*)d_in[15];
    const float* out_b2  = (const float*)d_in[16];
    float* out = (float*)d_out;

    float* ws = (float*)d_ws;
    size_t off = 0;
    auto alloc = [&](size_t n){ float* p = ws + off; off += n; return p; };
    u16*   encb      = (u16*)  alloc((size_t)BB*TENC*DENC/2);
    u16*   enc_projb = (u16*)  alloc((size_t)BB*TENC*AN/2);
    u16*   WdecTb    = (u16*)  alloc(256*128/2);
    float* WcombP    = alloc(576*1024);
    float* biasw     = alloc(1024);
    float* W1T       = alloc(512*256);
    float* W2T       = alloc(256*96);
    float* e0        = alloc(BB*TENC);
    float* e1        = alloc(BB*TENC);
    float* ctxU0     = alloc(BB*DENC);
    float* ctxU1     = alloc(BB*DENC);
    float* SU0       = alloc(BB);
    float* SU1       = alloc(BB);
    float* h0        = alloc(BB*HN);
    float* h1        = alloc(BB*HN);
    float* c_st      = alloc(BB*HN);
    float* hidA      = alloc(BB*HN);
    float* hidB      = alloc(BB*HN);
    if (off * sizeof(float) > ws_size) return;   // visible failure if ws too small

    k_prep<<<dim3(512), dim3(256), 0, stream>>>(enc, W_ih, W_hh, b_ih, b_hh, W_dec,
                                                out_w1, out_w2,
                                                encb, WdecTb, WcombP, biasw, W1T, W2T,
                                                e1, SU1);
    k_encproj<<<dim3(2048), dim3(128), 0, stream>>>(enc, W_enc, enc_projb);

    Params pr;
    pr.encb = encb; pr.enc_projb = enc_projb; pr.WdecTb = WdecTb;
    pr.conv_w = conv_w; pr.W_loc = W_loc; pr.v_w = v_w;
    pr.lengths = lengths; pr.targets = targets; pr.emb = emb;
    pr.WcombP = WcombP; pr.biasw = biasw;
    pr.W1T = W1T; pr.out_b1 = out_b1; pr.W2T = W2T; pr.out_b2 = out_b2;
    pr.e0 = e0; pr.e1 = e1; pr.ctxU0 = ctxU0; pr.ctxU1 = ctxU1;
    pr.SU0 = SU0; pr.SU1 = SU1; pr.h0 = h0; pr.h1 = h1;
    pr.c_st = c_st; pr.hidA = hidA; pr.hidB = hidB; pr.out = out;

    void* args[] = { (void*)&pr };
    hipError_t err = hipLaunchCooperativeKernel((const void*)k_loop, dim3(512), dim3(256),
                                                args, 0, stream);
    if (err != hipSuccess){
        // deterministic fallback: same phase code, per-step launches
        for (int t = 0; t <= 256; t++){
            k_cell_step<<<dim3(512), dim3(256), 0, stream>>>(pr, t);
            if (t <= 254)
                k_att_step<<<dim3(512), dim3(256), 0, stream>>>(pr, t);
        }
    }
}

// Round 7
// 12086.868 us; speedup vs baseline: 7.8230x; 5.5786x over previous
//
#include <hip/hip_runtime.h>
#include <hip/hip_bf16.h>

#define BB   64
#define TENC 1024
#define DENC 256
#define HN   256
#define AN   128
#define NFC  10
#define EMBD 64
#define VN   96
#define TT   255

typedef unsigned short u16;

__device__ __forceinline__ float fsig(float x){ return 1.0f/(1.0f+__expf(-x)); }
__device__ __forceinline__ float ftanh(float x){ return 1.0f - 2.0f/(1.0f+__expf(2.0f*x)); }
__device__ __forceinline__ float b2f(u16 v){ return __uint_as_float(((unsigned)v) << 16); }
__device__ __forceinline__ u16 f2b(float x){
    __hip_bfloat16 h = __float2bfloat16(x);
    return *reinterpret_cast<u16*>(&h);
}
__device__ __forceinline__ float4 ld_bf4(const u16* p){
    ushort4 v = *(const ushort4*)p;
    return make_float4(b2f(v.x), b2f(v.y), b2f(v.z), b2f(v.w));
}

struct Params {
    const u16* encb; const u16* enc_projb; const u16* WdecTb;
    const float* conv_w; const float* W_loc; const float* v_w;
    const int* lengths; const int* targets; const float* emb;
    const float* WcombP; const float* biasw;
    const float* W1T; const float* out_b1; const float* W2T; const float* out_b2;
    float* e0; float* e1; float* ctxU0; float* ctxU1; float* SU0; float* SU1;
    float* h0; float* h1; float* c_st; float* hidA; float* hidB;
    float* out;
};

// ---------------- one-time prep ----------------
__global__ void k_prep(const float* __restrict__ enc,
                       const float* __restrict__ W_ih, const float* __restrict__ W_hh,
                       const float* __restrict__ b_ih, const float* __restrict__ b_hh,
                       const float* __restrict__ W_dec, const float* __restrict__ out_w1,
                       const float* __restrict__ out_w2,
                       u16* __restrict__ encb, u16* __restrict__ WdecTb,
                       float* __restrict__ WcombP, float* __restrict__ biasw,
                       float* __restrict__ W1T, float* __restrict__ W2T,
                       float* __restrict__ e_init, float* __restrict__ S_init)
{
    int tid = blockIdx.x*blockDim.x + threadIdx.x;
    int tot = blockDim.x*gridDim.x;
    for (size_t i = tid; i < (size_t)BB*TENC*DENC; i += tot) encb[i] = f2b(enc[i]);
    // WcombP[k][rowP], rowP = ug*16 + gidx*4 + ul  <->  g = gidx*256 + ug*4 + ul
    for (int i = tid; i < 576*1024; i += tot){
        int k = i >> 10, rp = i & 1023;
        int ug = rp >> 4, q = rp & 15, gidx = q >> 2, ul = q & 3;
        int g = gidx*256 + ug*4 + ul;
        WcombP[i] = (k < 320) ? W_ih[(size_t)g*320 + k] : W_hh[(size_t)g*256 + (k-320)];
    }
    for (int i = tid; i < 1024; i += tot) biasw[i] = b_ih[i] + b_hh[i];
    for (int i = tid; i < 256*128; i += tot){ int u = i>>7, a = i&127; WdecTb[i] = f2b(W_dec[a*256 + u]); }
    for (int i = tid; i < 512*256; i += tot){ int k = i>>8, r = i&255; W1T[i] = out_w1[(size_t)r*512 + k]; }
    for (int i = tid; i < 256*96;  i += tot){ int k = i/96, v = i - k*96; W2T[i] = out_w2[(size_t)v*256 + k]; }
    for (int i = tid; i < BB*TENC; i += tot) e_init[i] = 1.0f;
    for (int i = tid; i < BB; i += tot) S_init[i] = (float)TENC;
}

// ---------------- one-time: enc_projb[b,t,a] (bf16) ----------------
__global__ __launch_bounds__(128) void k_encproj(const float* __restrict__ enc,
                                                 const float* __restrict__ W_enc,
                                                 u16* __restrict__ enc_projb)
{
    __shared__ float rows[32][256];
    int r0 = blockIdx.x * 32;
    for (int i = threadIdx.x; i < 32*256; i += 128)
        rows[i>>8][i&255] = enc[(size_t)r0*256 + i];
    __syncthreads();
    int a = threadIdx.x;
    float acc[32];
    #pragma unroll
    for (int r=0;r<32;r++) acc[r]=0.f;
    const float* w = W_enc + a*256;
    for (int d=0; d<256; d+=4){
        float4 wv = *(const float4*)(w + d);
        #pragma unroll
        for (int r=0;r<32;r++){
            float4 rv = *(const float4*)(&rows[r][d]);
            acc[r] += wv.x*rv.x + wv.y*rv.y + wv.z*rv.z + wv.w*rv.w;
        }
    }
    for (int r=0;r<32;r++) enc_projb[(size_t)(r0+r)*AN + a] = f2b(acc[r]);
}

// ---------------- shared LDS layouts ----------------
union alignas(16) SMemCell {
    struct { float xh[8][584]; float part[4][16][9]; float gates[8][17]; } gat;
};
union alignas(16) SMemAtt {
    struct { float hdec[128]; float part[256]; float ehalo[68]; float cw[52];
             float loc[64][11]; float wlocT[10*128]; float evals[64];
             float ep[64][33]; float wacc[4][256]; } att;
    struct { float xh[8][520]; float part[4][16][9]; } hidm;
    struct { float hs[8][260]; float part[4][32][9]; } lgt;
};

// ---------------- k_cell: gates + LSTM, 512 blocks, t in [0,254] ----------------
__global__ __launch_bounds__(256) void k_cell(Params P, int t)
{
    __shared__ SMemCell u;
    const int blk = blockIdx.x, tid = threadIdx.x;
    const int wr = t & 1;
    const float* ctxU_r = wr ? P.ctxU0 : P.ctxU1;
    float*       ctxU_w = wr ? P.ctxU1 : P.ctxU0;
    const float* SU_r   = wr ? P.SU0   : P.SU1;
    float*       SU_w   = wr ? P.SU1   : P.SU0;
    const float* h_old  = wr ? P.h0    : P.h1;
    float*       h_new  = wr ? P.h1    : P.h0;

    const int ug = blk & 63, bg = blk >> 6;
    const int b0 = bg*8;
    if (ug == 1){   // zero next-step accumulators for this batch group
        for (int i = tid; i < 8*DENC; i += 256) ctxU_w[b0*DENC + i] = 0.f;
        if (tid < 8) SU_w[b0 + tid] = 0.f;
    }
    for (int i = tid; i < 8*EMBD; i += 256){
        int bl = i>>6, j = i&63;
        int tok = P.targets[(b0+bl)*256 + t];
        u.gat.xh[bl][j] = P.emb[tok*EMBD + j];
    }
    for (int i = tid; i < 8*HN; i += 256){
        int bl = i>>8, d = i&255;
        u.gat.xh[bl][320+d] = (t == 0) ? 0.f : h_old[(b0+bl)*HN + d];
    }
    for (int i = tid; i < 8*DENC; i += 256){
        int bl = i>>8, d = i&255;
        u.gat.xh[bl][64+d] = (t == 0) ? 0.f
            : ctxU_r[(b0+bl)*DENC + d] * (1.0f/SU_r[b0+bl]);
    }
    __syncthreads();
    {
        const int kq = tid >> 6, lane = tid & 63, rl = lane & 15, blq = lane >> 4;
        const int rowP = ug*16 + rl, bl0 = blq*2;
        const float* wp  = P.WcombP + (size_t)(kq*144)*1024 + rowP;
        const float* x0p = &u.gat.xh[bl0][kq*144];
        const float* x1p = &u.gat.xh[bl0+1][kq*144];
        float s0 = 0.f, s1 = 0.f;
        for (int k = 0; k < 144; k += 4){
            float w0 = wp[0], w1 = wp[1024], w2 = wp[2048], w3 = wp[3072]; wp += 4096;
            float4 xa = *(const float4*)(x0p + k);
            float4 xb = *(const float4*)(x1p + k);
            s0 += w0*xa.x + w1*xa.y + w2*xa.z + w3*xa.w;
            s1 += w0*xb.x + w1*xb.y + w2*xb.z + w3*xb.w;
        }
        u.gat.part[kq][rl][bl0] = s0; u.gat.part[kq][rl][bl0+1] = s1;
    }
    __syncthreads();
    if (tid < 128){
        int bl = tid >> 4, rl = tid & 15;
        float s = u.gat.part[0][rl][bl] + u.gat.part[1][rl][bl]
                + u.gat.part[2][rl][bl] + u.gat.part[3][rl][bl];
        int gidx = rl >> 2, ul = rl & 3;
        u.gat.gates[bl][rl] = s + P.biasw[gidx*256 + ug*4 + ul];
    }
    __syncthreads();
    if (tid < 32){
        int bl = tid >> 2, ul = tid & 3;
        int bgl = b0 + bl, unit = ug*4 + ul;
        float gi = u.gat.gates[bl][0+ul],  gf = u.gat.gates[bl][4+ul];
        float gg = u.gat.gates[bl][8+ul],  go = u.gat.gates[bl][12+ul];
        float cold = (t == 0) ? 0.f : P.c_st[bgl*HN + unit];
        float cn = fsig(gf)*cold + fsig(gi)*ftanh(gg);
        P.c_st[bgl*HN + unit] = cn;
        h_new[bgl*HN + unit] = fsig(go)*ftanh(cn);
    }
}

// ---------------- k_att: attention [0,512) + hid(t-1) [512,640) + logits(t-2) [640,664) ----------------
__global__ __launch_bounds__(256) void k_att(Params P, int t)
{
    __shared__ SMemAtt u;
    const int blk = blockIdx.x, tid = threadIdx.x;
    const int wr = t & 1;
    const float* ctxU_r = wr ? P.ctxU0 : P.ctxU1;
    float*       ctxU_w = wr ? P.ctxU1 : P.ctxU0;
    const float* SU_r   = wr ? P.SU0   : P.SU1;
    float*       SU_w   = wr ? P.SU1   : P.SU0;
    const float* h_old  = wr ? P.h0    : P.h1;
    const float* h_new  = wr ? P.h1    : P.h0;
    const float* hid_pv = wr ? P.hidA  : P.hidB;
    float*       hid_nw = wr ? P.hidB  : P.hidA;
    const float* e_prev = wr ? P.e0    : P.e1;
    float*       e_new  = wr ? P.e1    : P.e0;

    if (blk < 512){                 // ---- attention for step t ----
        if (t > 254) return;
        const int b = blk >> 3;
        const int q = blk & 7;
        const int len = P.lengths[b];
        const float invS = 1.0f / SU_r[b];

        if (tid < 50) u.att.cw[tid] = P.conv_w[tid];
        for (int i = tid; i < 1280; i += 256){
            int f = i >> 7, a = i & 127;
            u.att.wlocT[f*128 + a] = P.W_loc[a*NFC + f];
        }
        {   // hdec partials: thread (a, half)
            int a = tid & 127, half = tid >> 7;
            const u16* wd = P.WdecTb + (size_t)(half*128)*AN + a;
            const float* hb = h_new + b*HN + half*128;
            float s0 = 0.f, s1 = 0.f;
            #pragma unroll 4
            for (int uu = 0; uu < 128; uu += 2){
                s0 += hb[uu]   * b2f(wd[(size_t)uu*AN]);
                s1 += hb[uu+1] * b2f(wd[(size_t)(uu+1)*AN]);
            }
            u.att.part[tid] = s0 + s1;
        }
        __syncthreads();
        if (tid < 128) u.att.hdec[tid] = u.att.part[tid] + u.att.part[tid+128];
        __syncthreads();

        for (int kk = 0; kk < 2; kk++){
            const int ch = q + 8*kk;
            const int t0 = ch*64;
            float* e_row = e_new + b*TENC + t0;
            int nv = len - t0; nv = nv < 0 ? 0 : (nv > 64 ? 64 : nv);
            if (nv == 0){
                if (tid < 64) e_row[tid] = 0.f;
                continue;
            }
            __syncthreads();
            if (tid < 68){
                int g = t0 - 2 + tid;
                u.att.ehalo[tid] = (g >= 0 && g < TENC) ? e_prev[b*TENC + g] : 0.f;
            }
            __syncthreads();
            if (tid < 64){
                #pragma unroll
                for (int f = 0; f < NFC; f++){
                    float s = 0.f;
                    #pragma unroll
                    for (int k2 = 0; k2 < 5; k2++) s += u.att.ehalo[tid+k2] * u.att.cw[f*5+k2];
                    u.att.loc[tid][f] = s * invS;
                }
            }
            __syncthreads();

            {   // energy partials: thread = (ag 32) x (pg 8)
                const int ag = tid & 31, pg = tid >> 5;
                const int a0 = ag*4;
                float4 hd4 = *(const float4*)&u.att.hdec[a0];
                float4 vv  = *(const float4*)(P.v_w + a0);
                const u16* epr = P.enc_projb + ((size_t)(b*TENC + t0))*AN + a0;
                #pragma unroll
                for (int i = 0; i < 8; i++){
                    int p = pg*8 + i;
                    if (p < nv){
                        float4 er = ld_bf4(epr + (size_t)p*AN);
                        float x0 = er.x + hd4.x, x1 = er.y + hd4.y;
                        float x2 = er.z + hd4.z, x3 = er.w + hd4.w;
                        #pragma unroll
                        for (int f = 0; f < NFC; f++){
                            float lf = u.att.loc[p][f];
                            const float* wla = &u.att.wlocT[f*128 + a0];
                            x0 += lf*wla[0]; x1 += lf*wla[1]; x2 += lf*wla[2]; x3 += lf*wla[3];
                        }
                        u.att.ep[p][ag] = vv.x*ftanh(x0) + vv.y*ftanh(x1)
                                        + vv.z*ftanh(x2) + vv.w*ftanh(x3);
                    }
                }
            }
            __syncthreads();

            if (tid < 64){
                int p = tid;
                float e = 0.f;
                if (p < nv){
                    float s0 = 0.f, s1 = 0.f;
                    #pragma unroll
                    for (int j = 0; j < 32; j += 2){ s0 += u.att.ep[p][j]; s1 += u.att.ep[p][j+1]; }
                    e = __expf(s0 + s1);   // |energy| <= sum|v| ~ 5.2
                }
                u.att.evals[p] = e;
                e_row[p] = e;
                float se = e;
                #pragma unroll
                for (int off = 32; off; off >>= 1) se += __shfl_xor(se, off);
                if (tid == 0) atomicAdd(SU_w + b, se);
            }
            __syncthreads();

            {   // unnormalized ctx: thread = (dq 64) x (pq 4)
                const int dq = tid & 63, pq = tid >> 6;
                const u16* encb = P.encb + ((size_t)(b*TENC + t0))*DENC + dq*4;
                float ax=0.f, ay=0.f, az=0.f, aw=0.f;
                for (int i = 0; i < 16; i++){
                    int p = pq + i*4;
                    if (p < nv){
                        float ev = u.att.evals[p];
                        float4 ex = ld_bf4(encb + (size_t)p*DENC);
                        ax += ev*ex.x; ay += ev*ex.y; az += ev*ex.z; aw += ev*ex.w;
                    }
                }
                float4 r; r.x=ax; r.y=ay; r.z=az; r.w=aw;
                *(float4*)&u.att.wacc[pq][dq*4] = r;
            }
            __syncthreads();
            {
                int d = tid;
                float s = u.att.wacc[0][d] + u.att.wacc[1][d]
                        + u.att.wacc[2][d] + u.att.wacc[3][d];
                atomicAdd(ctxU_w + b*DENC + d, s);
            }
            __syncthreads();
        }
        return;
    }

    if (blk < 640){                 // ---- hid(t-1): needs ctx(t-1), h(t-1) ----
        if (!(t >= 1 && t <= 255)) return;
        int hb = blk - 512;
        int bg = hb >> 4, rg = hb & 15;
        int b0 = bg*8, r0 = rg*16;
        for (int i = tid; i < 8*HN; i += 256){
            int bl = i>>8, d = i&255;
            u.hidm.xh[bl][d] = h_old[(b0+bl)*HN + d];
        }
        for (int i = tid; i < 8*DENC; i += 256){
            int bl = i>>8, d = i&255;
            u.hidm.xh[bl][256+d] = ctxU_r[(b0+bl)*DENC + d] * (1.0f/SU_r[b0+bl]);
        }
        __syncthreads();
        {
            const int kq = tid >> 6, lane = tid & 63, rl = lane & 15, blq = lane >> 4;
            const int bl0 = blq*2;
            const float* wp  = P.W1T + (size_t)(kq*128)*256 + (r0 + rl);
            const float* x0p = &u.hidm.xh[bl0][kq*128];
            const float* x1p = &u.hidm.xh[bl0+1][kq*128];
            float s0 = 0.f, s1 = 0.f;
            for (int k = 0; k < 128; k += 4){
                float w0 = wp[0], w1 = wp[256], w2 = wp[512], w3 = wp[768]; wp += 1024;
                float4 xa = *(const float4*)(x0p + k);
                float4 xb = *(const float4*)(x1p + k);
                s0 += w0*xa.x + w1*xa.y + w2*xa.z + w3*xa.w;
                s1 += w0*xb.x + w1*xb.y + w2*xb.z + w3*xb.w;
            }
            u.hidm.part[kq][rl][bl0] = s0; u.hidm.part[kq][rl][bl0+1] = s1;
        }
        __syncthreads();
        if (tid < 128){
            int bl = tid >> 4, rl = tid & 15;
            int r = r0 + rl;
            float s = u.hidm.part[0][rl][bl] + u.hidm.part[1][rl][bl]
                    + u.hidm.part[2][rl][bl] + u.hidm.part[3][rl][bl];
            hid_nw[(b0+bl)*HN + r] = ftanh(s + P.out_b1[r]);
        }
        return;
    }

    {                               // ---- logits(t-2): needs hid(t-2) ----
        if (t < 2) return;
        int lt = blk - 640;
        int bgr = lt/3, vg = lt%3;
        int b0 = bgr*8, v0 = vg*32;
        for (int i = tid; i < 8*HN; i += 256){
            int bl = i>>8, d = i&255;
            u.lgt.hs[bl][d] = hid_pv[(b0+bl)*HN + d];
        }
        __syncthreads();
        {
            const int kq = tid >> 6, lane = tid & 63, vl = lane & 31, blq = lane >> 5;
            const int bl0 = blq*4;
            const float* wp = P.W2T + (size_t)(kq*64)*96 + (v0 + vl);
            float a4[4] = {0.f,0.f,0.f,0.f};
            for (int k = 0; k < 64; k += 4){
                float w0 = wp[0], w1 = wp[96], w2 = wp[192], w3 = wp[288]; wp += 384;
                #pragma unroll
                for (int j = 0; j < 4; j++){
                    float4 x = *(const float4*)&u.lgt.hs[bl0+j][kq*64 + k];
                    a4[j] += w0*x.x + w1*x.y + w2*x.z + w3*x.w;
                }
            }
            #pragma unroll
            for (int j = 0; j < 4; j++) u.lgt.part[kq][vl][bl0+j] = a4[j];
        }
        __syncthreads();
        {
            int bl = tid >> 5, vl = tid & 31;
            int v = v0 + vl;
            float s = u.lgt.part[0][vl][bl] + u.lgt.part[1][vl][bl]
                    + u.lgt.part[2][vl][bl] + u.lgt.part[3][vl][bl];
            P.out[((size_t)(b0+bl)*TT + (t-2))*VN + v] = s + P.out_b2[v];
        }
    }
}

extern "C" void kernel_launch(void* const* d_in, const int* in_sizes, int n_in,
                              void* d_out, int out_size, void* d_ws, size_t ws_size,
                              hipStream_t stream)
{
    const float* enc     = (const float*)d_in[0];
    const int*   lengths = (const int*)  d_in[1];
    const int*   targets = (const int*)  d_in[2];
    const float* emb     = (const float*)d_in[3];
    const float* W_ih    = (const float*)d_in[4];
    const float* W_hh    = (const float*)d_in[5];
    const float* b_ih    = (const float*)d_in[6];
    const float* b_hh    = (const float*)d_in[7];
    const float* conv_w  = (const float*)d_in[8];
    const float* W_enc   = (const float*)d_in[9];
    const float* W_dec   = (const float*)d_in[10];
    const float* W_loc   = (const float*)d_in[11];
    const float* v_w     = (const float*)d_in[12];
    const float* out_w1  = (const float*)d_in[13];
    const float* out_b1  = (const float*)d_in[14];
    const float* out_w2  = (const float*)d_in[15];
    const float* out_b2  = (const float*)d_in[16];
    float* out = (float*)d_out;

    float* ws = (float*)d_ws;
    size_t off = 0;
    auto alloc = [&](size_t n){ float* p = ws + off; off += n; return p; };
    u16*   encb      = (u16*)  alloc((size_t)BB*TENC*DENC/2);
    u16*   enc_projb = (u16*)  alloc((size_t)BB*TENC*AN/2);
    u16*   WdecTb    = (u16*)  alloc(256*128/2);
    float* WcombP    = alloc(576*1024);
    float* biasw     = alloc(1024);
    float* W1T       = alloc(512*256);
    float* W2T       = alloc(256*96);
    float* e0        = alloc(BB*TENC);
    float* e1        = alloc(BB*TENC);
    float* ctxU0     = alloc(BB*DENC);
    float* ctxU1     = alloc(BB*DENC);
    float* SU0       = alloc(BB);
    float* SU1       = alloc(BB);
    float* h0        = alloc(BB*HN);
    float* h1        = alloc(BB*HN);
    float* c_st      = alloc(BB*HN);
    float* hidA      = alloc(BB*HN);
    float* hidB      = alloc(BB*HN);
    if (off * sizeof(float) > ws_size) return;   // visible failure if ws too small

    k_prep<<<dim3(512), dim3(256), 0, stream>>>(enc, W_ih, W_hh, b_ih, b_hh, W_dec,
                                                out_w1, out_w2,
                                                encb, WdecTb, WcombP, biasw, W1T, W2T,
                                                e1, SU1);
    k_encproj<<<dim3(2048), dim3(128), 0, stream>>>(enc, W_enc, enc_projb);

    Params pr;
    pr.encb = encb; pr.enc_projb = enc_projb; pr.WdecTb = WdecTb;
    pr.conv_w = conv_w; pr.W_loc = W_loc; pr.v_w = v_w;
    pr.lengths = lengths; pr.targets = targets; pr.emb = emb;
    pr.WcombP = WcombP; pr.biasw = biasw;
    pr.W1T = W1T; pr.out_b1 = out_b1; pr.W2T = W2T; pr.out_b2 = out_b2;
    pr.e0 = e0; pr.e1 = e1; pr.ctxU0 = ctxU0; pr.ctxU1 = ctxU1;
    pr.SU0 = SU0; pr.SU1 = SU1; pr.h0 = h0; pr.h1 = h1;
    pr.c_st = c_st; pr.hidA = hidA; pr.hidB = hidB; pr.out = out;

    for (int t = 0; t <= 256; t++){
        if (t <= 254)
            k_cell<<<dim3(512), dim3(256), 0, stream>>>(pr, t);
        k_att<<<dim3(664), dim3(256), 0, stream>>>(pr, t);
    }
}